// Round 14
// baseline (144.740 us; speedup 1.0000x reference)
//
#include <hip/hip_runtime.h>
#include <hip/hip_bf16.h>

#define N_NODES 50000
#define NPAD 50016          // Yc row stride: N_NODES padded; rows >= N_NODES are zero
#define DUMMY 50000         // dummy src index -> zero row (padding contributes 0)
#define DIM 256
#define N_EDGES 1600000
#define NBUK 196            // buckets of 256 nodes: 196*256 = 50176 >= 50000
#define CAP 10240           // fixed bucket region capacity (8-padded mean 9190 + 11 sigma)
#define CHUNK_E 4096        // edges per binning block
#define NBLK ((N_EDGES + CHUNK_E - 1) / CHUNK_E)   // 391
#define GEMM_BLKS ((N_NODES + 63) / 64)            // 782
#define NCHUNK 8            // Y column chunks (32 cols each), one per XCD
#define AGG_BPC 782         // aggregate blocks per chunk: 782*4 warps >= 3125 groups
#define NGROUP (N_NODES / 16)  // 3125 groups of 16 nodes
#define LROW 72             // LDS W-tile row stride in bf16 (144 B, not 0 mod 128B)

typedef float f32x4 __attribute__((ext_vector_type(4)));
typedef __bf16 bf16x8 __attribute__((ext_vector_type(8)));
typedef __bf16 bf16x4 __attribute__((ext_vector_type(4)));
typedef unsigned long long u64;
typedef unsigned int u32;
typedef unsigned short u16;

// ================= K1: place (391 blocks) | W-conv + Yc-pad (257 blocks) ======
// place has no upstream deps; W-conv/Yc-zero run in its shadow.
// bcur pre-zeroed by memset; bucket base b*CAP added in-kernel.
__global__ __launch_bounds__(256) void prep_k(const float* __restrict__ W,
                                              __bf16* __restrict__ Wbf,
                                              __bf16* __restrict__ Yc,
                                              const int* __restrict__ src,
                                              const int* __restrict__ dst,
                                              int* __restrict__ bcur,
                                              unsigned int* __restrict__ staged) {
    __shared__ int lh[NBUK];
    __shared__ int lbase[NBUK];

    if (blockIdx.x < NBLK) {
        // ---- place role ----
        int pb = blockIdx.x;
        for (int i = threadIdx.x; i < NBUK; i += 256) lh[i] = 0;
        __syncthreads();
        int base = pb * CHUNK_E;
        int end = base + CHUNK_E; if (end > N_EDGES) end = N_EDGES;
        for (int e = base + threadIdx.x; e < end; e += 256)
            atomicAdd(&lh[dst[e] >> 8], 1);
        __syncthreads();
        for (int i = threadIdx.x; i < NBUK; i += 256) {
            int c = lh[i];
            lbase[i] = c ? (atomicAdd(&bcur[i], c) + i * CAP) : 0;
            lh[i] = 0;                 // reuse as local cursor
        }
        __syncthreads();
        for (int e = base + threadIdx.x; e < end; e += 256) {
            int d = dst[e];
            int s = src[e];            // < 50000 -> fits in 16 bits
            int b = d >> 8;
            int p = atomicAdd(&lh[b], 1);
            staged[lbase[b] + p] = (unsigned int)s | ((unsigned int)(d & 255) << 16);
        }
    } else {
        int p = blockIdx.x - NBLK;     // 0..256
        if (p < 256) {
            int i = p * 256 + threadIdx.x;   // [0, 65536)
            Wbf[i] = (__bf16)W[i];
        } else {
            // zero the 16 pad rows per chunk: NCHUNK*16*32 = 4096 elems
            for (int i = threadIdx.x; i < NCHUNK * 16 * 32; i += 256) {
                int c = i >> 9;
                int rem = i & 511;
                Yc[(size_t)c * NPAD * 32 + (size_t)(N_NODES + (rem >> 5)) * 32 + (rem & 31)]
                    = (__bf16)0.0f;
            }
        }
    }
}

// ================= K2: gemm (782 blocks) | finalize (196 blocks) ==============
// Independent roles (gemm needs Wbf/feat; finalize needs staged/bcur) -> overlap.
__global__ __launch_bounds__(256) void gemmfin_k(const float* __restrict__ feat,
                                                 const __bf16* __restrict__ Wbf,
                                                 __bf16* __restrict__ Yc,
                                                 const unsigned int* __restrict__ staged,
                                                 const int* __restrict__ bcur,
                                                 int* __restrict__ offs,
                                                 u16* __restrict__ deg16,
                                                 u16* __restrict__ edge16) {
    __shared__ __bf16 lw[256 * LROW];    // 36 KB W K-quarter tile (gemm role)
    __shared__ int nh[256];              // finalize role
    __shared__ int nbase[256];
    __shared__ int sm[256];

    if (blockIdx.x < GEMM_BLKS) {
        // ---- GEMM role ----
        const int wid  = threadIdx.x >> 6;
        const int lane = threadIdx.x & 63;
        const int row0 = blockIdx.x * 64 + wid * 16;
        const int mrow = lane & 15;
        const int kgrp = lane >> 4;          // 0..3

        int arow = row0 + mrow;
        int arow_c = arow < N_NODES ? arow : (N_NODES - 1);
        const float* aptr = feat + (size_t)arow_c * DIM + kgrp * 8;

        const int t = threadIdx.x;
        const int srow = t >> 3;             // base row (stride 32 per iter)
        const int scb  = (t & 7) * 8;        // bf16 col offset within quarter

        f32x4 acc[16];
#pragma unroll
        for (int i = 0; i < 16; ++i) acc[i] = (f32x4)0.0f;

        for (int p = 0; p < 4; ++p) {
            f32x4 ar0 = *(const f32x4*)(aptr + (p * 2) * 32);
            f32x4 ar1 = *(const f32x4*)(aptr + (p * 2) * 32 + 4);
            f32x4 ar2 = *(const f32x4*)(aptr + (p * 2 + 1) * 32);
            f32x4 ar3 = *(const f32x4*)(aptr + (p * 2 + 1) * 32 + 4);

            if (p) __syncthreads();
#pragma unroll
            for (int i = 0; i < 8; ++i) {
                int row = srow + i * 32;
                uint4 v = *(const uint4*)(Wbf + (size_t)row * DIM + p * 64 + scb);
                *(uint4*)(lw + row * LROW + scb) = v;
            }
            __syncthreads();

            bf16x8 af0, af1;
            af0[0] = (__bf16)ar0[0]; af0[1] = (__bf16)ar0[1];
            af0[2] = (__bf16)ar0[2]; af0[3] = (__bf16)ar0[3];
            af0[4] = (__bf16)ar1[0]; af0[5] = (__bf16)ar1[1];
            af0[6] = (__bf16)ar1[2]; af0[7] = (__bf16)ar1[3];
            af1[0] = (__bf16)ar2[0]; af1[1] = (__bf16)ar2[1];
            af1[2] = (__bf16)ar2[2]; af1[3] = (__bf16)ar2[3];
            af1[4] = (__bf16)ar3[0]; af1[5] = (__bf16)ar3[1];
            af1[6] = (__bf16)ar3[2]; af1[7] = (__bf16)ar3[3];

#pragma unroll
            for (int nt = 0; nt < 16; ++nt) {
                const __bf16* lp = lw + (nt * 16 + mrow) * LROW + kgrp * 8;
                bf16x8 wf0 = *(const bf16x8*)(lp);
                bf16x8 wf1 = *(const bf16x8*)(lp + 32);
                acc[nt] = __builtin_amdgcn_mfma_f32_16x16x32_bf16(wf0, af0, acc[nt], 0, 0, 0);
                acc[nt] = __builtin_amdgcn_mfma_f32_16x16x32_bf16(wf1, af1, acc[nt], 0, 0, 0);
            }
        }

        const int node = row0 + mrow;
        if (node < N_NODES) {
#pragma unroll
            for (int nt = 0; nt < 16; ++nt) {
                int oc0 = nt * 16 + kgrp * 4;
                bf16x4 pv;
                pv[0] = (__bf16)acc[nt][0];
                pv[1] = (__bf16)acc[nt][1];
                pv[2] = (__bf16)acc[nt][2];
                pv[3] = (__bf16)acc[nt][3];
                __bf16* yp = Yc + (size_t)(oc0 >> 5) * NPAD * 32
                                + (size_t)node * 32 + (oc0 & 31);
                *(bf16x4*)yp = pv;
            }
        }
    } else {
        // ---- finalize role: node offsets/degrees + u16 edge lists (8-padded) ----
        int t = threadIdx.x, b = blockIdx.x - GEMM_BLKS;
        int beg = b * CAP;
        int cnt = bcur[b];             // pure count (memset-0 based)
        nh[t] = 0;
        __syncthreads();
        for (int i = t; i < cnt; i += 256)
            atomicAdd(&nh[staged[beg + i] >> 16], 1);
        __syncthreads();
        int v = nh[t];
        int v8 = (v + 7) & ~7;         // padded count (multiple of 8)
        sm[t] = v8;
        __syncthreads();
        for (int off = 1; off < 256; off <<= 1) {
            int x = (t >= off) ? sm[t - off] : 0;
            __syncthreads();
            sm[t] += x;
            __syncthreads();
        }
        nbase[t] = sm[t] - v8;         // exclusive prefix of padded counts (8-aligned)
        int node = (b << 8) + t;
        if (node < N_NODES) {
            offs[node]  = beg + nbase[t];
            deg16[node] = (u16)v;
        }
        for (int i = v; i < v8; ++i)
            edge16[beg + nbase[t] + i] = (u16)DUMMY;
        nh[t] = 0;                     // reuse as per-node cursor
        __syncthreads();
        for (int i = t; i < cnt; i += 256) {
            unsigned int u = staged[beg + i];
            int dl = (int)(u >> 16);
            int p = atomicAdd(&nh[dl], 1);
            edge16[beg + nbase[dl] + p] = (u16)(u & 0xFFFFu);
        }
    }
}

// ================= K3: per-node gather-mean + bias, 16-deep forced ============
// chunk = blockIdx & 7 (XCD round-robin); per-XCD working set = 3.2MB (L2-resident)
// wave = 16 nodes; segment (4 lanes) owns one node; lane covers 8 cols (16B/edge).
// sched_barrier(0) pins ALL 16 gathers + 4 edge-word prefetches issued before
// any accumulate (compiler otherwise sinks loads to save registers, R10/R13).
#define GQ(ev) (*(const uint4*)(Ybase + (size_t)((u32)(ev) & 0xffffu) * 32 + cl))
#define ACCQ(q) do { \
    a0 += __uint_as_float((q).x << 16); a1 += __uint_as_float((q).x); \
    a2 += __uint_as_float((q).y << 16); a3 += __uint_as_float((q).y); \
    a4 += __uint_as_float((q).z << 16); a5 += __uint_as_float((q).z); \
    a6 += __uint_as_float((q).w << 16); a7 += __uint_as_float((q).w); \
} while (0)

__global__ __launch_bounds__(256) void aggregate_k(const __bf16* __restrict__ Yc,
                                                   const int* __restrict__ offs,
                                                   const u16* __restrict__ deg16,
                                                   const u16* __restrict__ edge16,
                                                   const float* __restrict__ bias,
                                                   float* __restrict__ out) {
    const int chunk = blockIdx.x & 7;
    const int bic   = blockIdx.x >> 3;      // block index within chunk
    const int wid   = threadIdx.x >> 6;
    const int lane  = threadIdx.x & 63;
    const int seg   = lane >> 2;            // node slot 0..15
    const int cl    = (lane & 3) * 8;       // bf16 col within chunk: 0,8,16,24

    const int g = bic * 4 + wid;            // one group per warp
    if (g >= NGROUP) return;
    const int node = g * 16 + seg;

    const __bf16* Ybase = Yc + (size_t)chunk * NPAD * 32;
    const float* bp = bias + chunk * 32 + cl;
    const f32x4 bv0 = *(const f32x4*)bp;
    const f32x4 bv1 = *(const f32x4*)(bp + 4);

    const int beg = offs[node];
    const int dg  = (int)deg16[node];

    float a0 = 0.f, a1 = 0.f, a2 = 0.f, a3 = 0.f;
    float a4 = 0.f, a5 = 0.f, a6 = 0.f, a7 = 0.f;

    f32x4 r0, r1;
    if (dg > 0) {
        const int nb8 = (dg + 7) >> 3;      // number of 8-edge batches
        const int npair = nb8 >> 1;
        const int odd = nb8 & 1;
        int j = beg;
        u64 eA = *(const u64*)(edge16 + j);
        u64 eB = *(const u64*)(edge16 + j + 4);
        u64 eC = *(const u64*)(edge16 + j + 8);
        u64 eD = *(const u64*)(edge16 + j + 12);
        for (int p = 0; p < npair; ++p) {
            u64 nA = *(const u64*)(edge16 + j + 16);
            u64 nB = *(const u64*)(edge16 + j + 20);
            u64 nC = *(const u64*)(edge16 + j + 24);
            u64 nD = *(const u64*)(edge16 + j + 28);
            uint4 q0 = GQ(eA);       uint4 q1 = GQ(eA >> 16);
            uint4 q2 = GQ(eA >> 32); uint4 q3 = GQ(eA >> 48);
            uint4 q4 = GQ(eB);       uint4 q5 = GQ(eB >> 16);
            uint4 q6 = GQ(eB >> 32); uint4 q7 = GQ(eB >> 48);
            uint4 q8 = GQ(eC);       uint4 q9 = GQ(eC >> 16);
            uint4 qa = GQ(eC >> 32); uint4 qb = GQ(eC >> 48);
            uint4 qc = GQ(eD);       uint4 qd = GQ(eD >> 16);
            uint4 qe = GQ(eD >> 32); uint4 qf = GQ(eD >> 48);
            __builtin_amdgcn_sched_barrier(0);   // all 20 loads issued before ACC
            ACCQ(q0); ACCQ(q1); ACCQ(q2); ACCQ(q3);
            ACCQ(q4); ACCQ(q5); ACCQ(q6); ACCQ(q7);
            ACCQ(q8); ACCQ(q9); ACCQ(qa); ACCQ(qb);
            ACCQ(qc); ACCQ(qd); ACCQ(qe); ACCQ(qf);
            j += 16;
            eA = nA; eB = nB; eC = nC; eD = nD;
        }
        if (odd) {
            uint4 q0 = GQ(eA);       uint4 q1 = GQ(eA >> 16);
            uint4 q2 = GQ(eA >> 32); uint4 q3 = GQ(eA >> 48);
            uint4 q4 = GQ(eB);       uint4 q5 = GQ(eB >> 16);
            uint4 q6 = GQ(eB >> 32); uint4 q7 = GQ(eB >> 48);
            ACCQ(q0); ACCQ(q1); ACCQ(q2); ACCQ(q3);
            ACCQ(q4); ACCQ(q5); ACCQ(q6); ACCQ(q7);
        }
        float inv = 1.0f / (float)dg;
        r0[0] = a0 * inv + bv0[0];
        r0[1] = a1 * inv + bv0[1];
        r0[2] = a2 * inv + bv0[2];
        r0[3] = a3 * inv + bv0[3];
        r1[0] = a4 * inv + bv1[0];
        r1[1] = a5 * inv + bv1[1];
        r1[2] = a6 * inv + bv1[2];
        r1[3] = a7 * inv + bv1[3];
    } else {
        uint4 q = *(const uint4*)(Ybase + (size_t)node * 32 + cl);
        r0[0] = __uint_as_float(q.x << 16) + bv0[0];
        r0[1] = __uint_as_float(q.x & 0xffff0000u) + bv0[1];
        r0[2] = __uint_as_float(q.y << 16) + bv0[2];
        r0[3] = __uint_as_float(q.y & 0xffff0000u) + bv0[3];
        r1[0] = __uint_as_float(q.z << 16) + bv1[0];
        r1[1] = __uint_as_float(q.z & 0xffff0000u) + bv1[1];
        r1[2] = __uint_as_float(q.w << 16) + bv1[2];
        r1[3] = __uint_as_float(q.w & 0xffff0000u) + bv1[3];
    }
    float* op = out + (size_t)node * DIM + chunk * 32 + cl;
    *(f32x4*)op = r0;
    *(f32x4*)(op + 4) = r1;
}

static inline size_t align64(size_t x) { return (x + 63) & ~(size_t)63; }

extern "C" void kernel_launch(void* const* d_in, const int* in_sizes, int n_in,
                              void* d_out, int out_size, void* d_ws, size_t ws_size,
                              hipStream_t stream) {
    const float* feature = (const float*)d_in[0];
    const int*   src     = (const int*)d_in[1];
    const int*   dst     = (const int*)d_in[2];
    const float* W       = (const float*)d_in[3];
    const float* b       = (const float*)d_in[4];
    float* out = (float*)d_out;

    // workspace layout (~38.2 MB total)
    char* ws = (char*)d_ws;
    __bf16* Yc  = (__bf16*)ws;               ws += align64((size_t)NCHUNK * NPAD * 32 * 2);
    __bf16* Wbf = (__bf16*)ws;               ws += align64((size_t)DIM * DIM * 2);
    int* offs     = (int*)ws;                ws += align64((size_t)N_NODES * 4);
    u16* deg16    = (u16*)ws;                ws += align64((size_t)N_NODES * 2);
    int* bcur     = (int*)ws;                ws += align64((size_t)NBUK * 4);
    unsigned int* staged = (unsigned int*)ws; ws += align64((size_t)NBUK * CAP * 4);
    u16* edge16   = (u16*)ws;                ws += align64((size_t)NBUK * CAP * 2 + 128);

    hipMemsetAsync(bcur, 0, (size_t)NBUK * 4, stream);
    prep_k<<<NBLK + 257, 256, 0, stream>>>(W, Wbf, Yc, src, dst, bcur, staged);
    gemmfin_k<<<GEMM_BLKS + NBUK, 256, 0, stream>>>(feature, Wbf, Yc, staged, bcur,
                                                    offs, deg16, edge16);
    aggregate_k<<<NCHUNK * AGG_BPC, 256, 0, stream>>>(Yc, offs, deg16, edge16, b, out);
}